// Round 23
// baseline (411.664 us; speedup 1.0000x reference)
//
#include <hip/hip_runtime.h>

typedef unsigned short us;
typedef us us4 __attribute__((ext_vector_type(4)));
typedef us us8 __attribute__((ext_vector_type(8)));
typedef short bf16x8 __attribute__((ext_vector_type(8)));
typedef float f32x4 __attribute__((ext_vector_type(4)));

#define DEVI static __device__ __forceinline__

// constants for this problem instance
#define BB 16
#define NN 4096
#define PP 256
#define CC 8
#define MM (BB * NN)   // 65536

DEVI float bf2f(us u) { unsigned x = ((unsigned)u) << 16; return __builtin_bit_cast(float, x); }
DEVI us f2bf(float f) {
  unsigned x = __builtin_bit_cast(unsigned, f);
  x += 0x7fffu + ((x >> 16) & 1u);   // round to nearest even
  return (us)(x >> 16);
}

DEVI void gload_lds16(const void* g, void* l) {
  __builtin_amdgcn_global_load_lds(
      (const __attribute__((address_space(1))) void*)g,
      (__attribute__((address_space(3))) void*)l, 16, 0, 0);
}

DEVI float sigf(float x) { return 1.f / (1.f + __expf(-x)); }
DEVI float tanhfast(float a) {
  float aa = fabsf(a);
  float t = 1.f - 2.f / (1.f + __expf(2.f * aa));
  return copysignf(t, a);
}

DEVI void raw_barrier() {
  __builtin_amdgcn_sched_barrier(0);
  __builtin_amdgcn_s_barrier();      // RAW barrier: no implicit vmcnt(0) drain
  __builtin_amdgcn_sched_barrier(0);
}

// ---------------- weight prep ---------------------------------------------------
// Wcat[256][512] = [W_parent | W_nbr]; bcat = bpar + bnbr.
// Packed gates weights (192-row B-tiles, no dead rows):
//   Wgh[768][256] (h-half, from Wih) / Wgs[768][256] (s-half, from Whh):
//   row R -> J16 = R/48, slot = (R/16)%3; j_out = J16*16 + (R&15);
//   slot 0 = r, slot 1 = z, slot 2 = n (xn / hn).
__global__ void k_prep(const float* __restrict__ Wres,
                       const float* __restrict__ Wpar, const float* __restrict__ bpar,
                       const float* __restrict__ Wnbr, const float* __restrict__ bnbr,
                       const float* __restrict__ Wih, const float* __restrict__ Whh,
                       const float* __restrict__ bih, const float* __restrict__ bhh,
                       us* __restrict__ Wr, us* __restrict__ Wcat, float* __restrict__ bcat,
                       us* __restrict__ Wgh, us* __restrict__ Wgs, float* __restrict__ bg) {
  int tid = blockIdx.x * blockDim.x + threadIdx.x;
  int nth = gridDim.x * blockDim.x;
  for (int i = tid; i < 256 * 256; i += nth) Wr[i] = f2bf(Wres[i]);
  for (int i = tid; i < 256 * 512; i += nth) {
    int o = i >> 9, k = i & 511;
    float v = (k < 256) ? Wpar[o * 256 + k] : Wnbr[o * 256 + (k - 256)];
    Wcat[i] = f2bf(v);
  }
  for (int i = tid; i < 256; i += nth) bcat[i] = bpar[i] + bnbr[i];
  for (int i = tid; i < 768 * 256; i += nth) {
    int R = i >> 8, k = i & 255;
    int j = (R / 48) * 16 + (R & 15);
    int slot = (R >> 4) % 3;                     // 0=r 1=z 2=n
    Wgh[i] = f2bf(Wih[(size_t)(slot * 256 + j) * 256 + k]);
    Wgs[i] = f2bf(Whh[(size_t)(slot * 256 + j) * 256 + k]);
  }
  for (int i = tid; i < 1024; i += nth) {
    int g = (i >> 4) & 3, j = ((i >> 6) << 4) + (i & 15);
    float v;
    if (g == 0)      v = bih[j] + bhh[j];
    else if (g == 1) v = bih[256 + j] + bhh[256 + j];
    else if (g == 2) v = bih[512 + j];
    else             v = bhh[512 + j];
    bg[i] = v;
  }
}

// ---------------- MFMA K-step (256x256 tile), full 4-j (resize) ----------------
DEVI void mma8(const us* As, const us* Bs, int wr, int wc, int l,
               f32x4 (&acc)[8][4]) {
#pragma unroll
  for (int ks = 0; ks < 2; ++ks) {
    bf16x8 af[8], bfr[4];
#pragma unroll
    for (int i = 0; i < 8; ++i) {
      int row = wr * 128 + i * 16 + (l & 15);
      int kb = ((ks * 32 + (l >> 4) * 8) * 2) ^ ((row & 7) << 4);  // swizzled read
      af[i] = *(const bf16x8*)((const char*)As + row * 128 + kb);
    }
#pragma unroll
    for (int j = 0; j < 4; ++j) {
      int row = wc * 64 + j * 16 + (l & 15);
      int kb = ((ks * 32 + (l >> 4) * 8) * 2) ^ ((row & 7) << 4);
      bfr[j] = *(const bf16x8*)((const char*)Bs + row * 128 + kb);
    }
#pragma unroll
    for (int i = 0; i < 8; ++i)
#pragma unroll
      for (int j = 0; j < 4; ++j)
        acc[i][j] = __builtin_amdgcn_mfma_f32_16x16x32_bf16(af[i], bfr[j], acc[i][j], 0, 0, 0);
  }
}

// ---------------- MFMA K-step (sgemm, 128x128 tile): per-wave 64x32 ------------
DEVI void mma_s(const us* As, const us* Bs, int wr, int wc, int l,
                f32x4 (&acc)[4][2]) {
#pragma unroll
  for (int ks = 0; ks < 2; ++ks) {
    bf16x8 af[4], bfr[2];
#pragma unroll
    for (int i = 0; i < 4; ++i) {
      int row = wr * 64 + i * 16 + (l & 15);
      int kb = ((ks * 32 + (l >> 4) * 8) * 2) ^ ((row & 7) << 4);
      af[i] = *(const bf16x8*)((const char*)As + row * 128 + kb);
    }
#pragma unroll
    for (int j = 0; j < 2; ++j) {
      int row = wc * 32 + j * 16 + (l & 15);
      int kb = ((ks * 32 + (l >> 4) * 8) * 2) ^ ((row & 7) << 4);
      bfr[j] = *(const bf16x8*)((const char*)Bs + row * 128 + kb);
    }
    __builtin_amdgcn_s_setprio(1);
#pragma unroll
    for (int i = 0; i < 4; ++i)
#pragma unroll
      for (int j = 0; j < 2; ++j)
        acc[i][j] = __builtin_amdgcn_mfma_f32_16x16x32_bf16(af[i], bfr[j], acc[i][j], 0, 0, 0);
    __builtin_amdgcn_s_setprio(0);
  }
}

// ---------------- MFMA phase (gates): one ks, per-wave M=64, packed B ----------
template <int HN, int KS>
DEVI void mma4g_ks(const us* As, const us* Bs, int wr, int wc, int l,
                   f32x4 (&acc)[4][4]) {
  bf16x8 af[4], bfr[3];
#pragma unroll
  for (int i = 0; i < 4; ++i) {
    int row = wr * 64 + i * 16 + (l & 15);
    int kb = ((KS * 32 + (l >> 4) * 8) * 2) ^ ((row & 7) << 4);
    af[i] = *(const bf16x8*)((const char*)As + row * 128 + kb);
  }
#pragma unroll
  for (int j = 0; j < 3; ++j) {
    int row = wc * 48 + j * 16 + (l & 15);
    int kb = ((KS * 32 + (l >> 4) * 8) * 2) ^ ((row & 7) << 4);
    bfr[j] = *(const bf16x8*)((const char*)Bs + row * 128 + kb);
  }
  __builtin_amdgcn_s_setprio(1);
#pragma unroll
  for (int i = 0; i < 4; ++i)
#pragma unroll
    for (int j = 0; j < 3; ++j) {
      int aj = (j < 2) ? j : (HN ? 3 : 2);
      acc[i][aj] = __builtin_amdgcn_mfma_f32_16x16x32_bf16(af[i], bfr[j], acc[i][aj], 0, 0, 0);
    }
  __builtin_amdgcn_s_setprio(0);
}

// ---------------- resize GEMM: h0 = x(f32) @ Wr^T + bres -----------------------
__global__ __launch_bounds__(512, 2)
void k_gemm0(const float* __restrict__ x, const us* __restrict__ Bw,
             const float* __restrict__ bias, us* __restrict__ outBf) {
  __shared__ __align__(16) us As[256 * 64];
  __shared__ __align__(16) us Bs[256 * 64];
  int tid = threadIdx.x;
  int w = tid >> 6, l = tid & 63;
  int wr = w >> 2, wc = w & 3;
  int bid = blockIdx.x;
  int per = gridDim.x >> 3;
  int mi = (bid & 7) * per + (bid >> 3);
  int mBase = mi * 256;
  f32x4 acc[8][4] = {};

#pragma unroll
  for (int t = 0; t < 4; ++t) {
    int kt = t * 64;
#pragma unroll
    for (int c = 0; c < 4; ++c) {
      int row = c * 64 + (tid >> 3);
      int kbb = ((tid & 7) * 16) ^ ((row & 7) << 4);   // bf16-byte offset (swizzled src)
      const float* src = x + (size_t)(mBase + row) * 256 + kt + (kbb >> 1);
      float4 a = *(const float4*)src;
      float4 b = *(const float4*)(src + 4);
      us8 v;
      v[0] = f2bf(a.x); v[1] = f2bf(a.y); v[2] = f2bf(a.z); v[3] = f2bf(a.w);
      v[4] = f2bf(b.x); v[5] = f2bf(b.y); v[6] = f2bf(b.z); v[7] = f2bf(b.w);
      *(us8*)((char*)As + row * 128 + (tid & 7) * 16) = v;  // linear dest
      int kb = ((tid & 7) * 16) ^ ((row & 7) << 4);
      gload_lds16((const char*)(Bw + (size_t)row * 256 + kt) + kb,
                  (char*)Bs + row * 128 + (tid & 7) * 16);
    }
    asm volatile("s_waitcnt vmcnt(0)" ::: "memory");
    __syncthreads();                  // drains lgkm (ds_writes) + barrier
    mma8(As, Bs, wr, wc, l, acc);
    __syncthreads();
  }

  int rBase0 = mBase + wr * 128;
  int cBase0 = wc * 64;
#pragma unroll
  for (int i = 0; i < 8; ++i)
#pragma unroll
    for (int j = 0; j < 4; ++j) {
      int col = cBase0 + j * 16 + (l & 15);
      int row0 = rBase0 + i * 16 + ((l >> 4) << 2);
      float bb = bias[col];
#pragma unroll
      for (int e = 0; e < 4; ++e)
        outBf[(size_t)(row0 + e) * 256 + col] = f2bf(acc[i][j][e] + bb);
    }
}

// ---------------- s GEMM: s = [h[par] | avg(h[children])] @ Wcat^T + bcat ------
// R23: R22-regime decomposition. 1024 blocks (512 m-tiles x 2 n-tiles) of
// 128M x 128N; 8 waves as 2(M)x4(N), per-wave 64x32 -> acc[4][2]=32 AGPR.
// LDS 64 KB (A 2x16 + B 2x16) -> 2 blocks/CU = 4 waves/SIMD (R22 mechanism).
// Children-average inlined in tiles 4-7 staging (duplicated across the 2
// n-blocks — L2-hot, amortized by 2x occupancy). Counted vmcnt: gload tiles
// leave 4 in flight; gather tiles leave 2 (child reg-loads self-drain).
__global__ __launch_bounds__(512, 2)
void k_sgemm(const us* __restrict__ h, const int* __restrict__ par,
             const int* __restrict__ chd, const int* __restrict__ cnt,
             const us* __restrict__ Wcat, const float* __restrict__ bcat,
             us* __restrict__ outBf, float* __restrict__ outF, int writeF32) {
  __shared__ __align__(16) us As[2][128 * 64];   // 32 KB
  __shared__ __align__(16) us Bs[2][128 * 64];   // 32 KB
  int tid = threadIdx.x;
  int w = tid >> 6, l = tid & 63;
  int wr = w >> 2, wc = w & 3;                   // 2(M) x 4(N)
  int bid = blockIdx.x;
  int per = gridDim.x >> 3;
  int g = (bid & 7) * per + (bid >> 3);
  int mi = g >> 1, ni = g & 1;                   // 512 m x 2 n
  int mBase = mi * 128, nBase = ni * 128;
  int bb = (mBase >> 12) << 12;                  // batch base row
  f32x4 acc[4][2] = {};

  int prow[2];
#pragma unroll
  for (int c = 0; c < 2; ++c)
    prow[c] = bb + par[mBase + c * 64 + (tid >> 3)];

  auto stageB = [&](int t) {
    int kt = t * 64, buf = t & 1;
#pragma unroll
    for (int c = 0; c < 2; ++c) {
      int row = c * 64 + (tid >> 3);
      int kb = ((tid & 7) * 16) ^ ((row & 7) << 4);
      gload_lds16((const char*)(Wcat + (size_t)(nBase + row) * 512 + kt) + kb,
                  (char*)Bs[buf] + row * 128 + (tid & 7) * 16);
    }
  };
  auto stageG = [&](int t) {          // tiles 0..3: h[parent] via gload (GA)
    int kt = t * 64, buf = t & 1;
#pragma unroll
    for (int c = 0; c < 2; ++c) {
      int row = c * 64 + (tid >> 3);
      int kb = ((tid & 7) * 16) ^ ((row & 7) << 4);
      gload_lds16((const char*)(h + (size_t)prow[c] * 256 + kt) + kb,
                  (char*)As[buf] + row * 128 + (tid & 7) * 16);
    }
    stageB(t);
  };
  auto stageN = [&](int t) {          // tiles 4..7: inline children-average
    int kt = t * 64, buf = t & 1;
    int kOffBase = kt - 256;
#pragma unroll
    for (int c = 0; c < 2; ++c) {
      int row = c * 64 + (tid >> 3);
      int m = mBase + row;
      int kbb = ((tid & 7) * 16) ^ ((row & 7) << 4);
      const us* hb = h + (size_t)bb * 256 + kOffBase + (kbb >> 1);
      int4 c0 = *(const int4*)(chd + (size_t)m * CC);
      int4 c1 = *(const int4*)(chd + (size_t)m * CC + 4);
      int ci[8] = {c0.x, c0.y, c0.z, c0.w, c1.x, c1.y, c1.z, c1.w};
      int cn = cnt[m];
      float aa[8] = {0.f, 0.f, 0.f, 0.f, 0.f, 0.f, 0.f, 0.f};
#pragma unroll
      for (int r2 = 0; r2 < 2; ++r2) {           // two rounds of 4 children
        us8 cv[4];
#pragma unroll
        for (int i2 = 0; i2 < 4; ++i2)
          cv[i2] = *(const us8*)(hb + (size_t)ci[r2 * 4 + i2] * 256);
#pragma unroll
        for (int i2 = 0; i2 < 4; ++i2) {
          float wgt = (r2 * 4 + i2 < cn) ? 1.f : 0.f;
#pragma unroll
          for (int e = 0; e < 8; ++e) aa[e] += wgt * bf2f(cv[i2][e]);
        }
      }
      float inv = 1.f / (float)cn;
      us8 nb;
#pragma unroll
      for (int e = 0; e < 8; ++e) nb[e] = f2bf(aa[e] * inv);
      *(us8*)((char*)As[buf] + row * 128 + (tid & 7) * 16) = nb;
    }
    asm volatile("s_waitcnt lgkmcnt(0)" ::: "memory");  // ds_writes done pre-barrier
    stageB(t);
  };

  stageG(0);
#pragma unroll
  for (int t = 0; t < 8; ++t) {
    if (t + 1 < 8) {
      if (t + 1 < 4) stageG(t + 1);
      else           stageN(t + 1);
    }
    if (t + 1 < 4)      asm volatile("s_waitcnt vmcnt(4)" ::: "memory");
    else if (t < 7)     asm volatile("s_waitcnt vmcnt(2)" ::: "memory");
    else                asm volatile("s_waitcnt vmcnt(0)" ::: "memory");
    raw_barrier();
    mma_s(As[t & 1], Bs[t & 1], wr, wc, l, acc);
    raw_barrier();
  }

  int rBase0 = mBase + wr * 64;
  int cBase0 = nBase + wc * 32;
#pragma unroll
  for (int i = 0; i < 4; ++i)
#pragma unroll
    for (int j = 0; j < 2; ++j) {
      int col = cBase0 + j * 16 + (l & 15);
      int row0 = rBase0 + i * 16 + ((l >> 4) << 2);
      float bbia = bcat[col];
#pragma unroll
      for (int e = 0; e < 4; ++e) {
        float v = acc[i][j][e] + bbia;
        size_t off = (size_t)(row0 + e) * 256 + col;
        outBf[off] = f2bf(v);
        if (writeF32) outF[off] = v;
      }
    }
}

// ---------------- gates GEMM: [h|s] @ packed-Wg, 128-row tile, 8 waves ---------
// R22 form — best measured (80 µs, zero spill, 4 waves/SIMD). Unchanged.
__global__ __launch_bounds__(512, 2)
void k_gates(const us* __restrict__ h, const us* __restrict__ s,
             const us* __restrict__ Wgh, const us* __restrict__ Wgs,
             const float* __restrict__ bg,
             us* __restrict__ outBf, float* __restrict__ outF,
             const us* __restrict__ svBf, const float* __restrict__ sF,
             int finalIt) {
  __shared__ __align__(16) us As[2][128 * 64];   // 32 KB
  __shared__ __align__(16) us Bs[2][192 * 64];   // 48 KB  (total 80 KB)
  int tid = threadIdx.x;
  int w = tid >> 6, l = tid & 63;
  int wr = w >> 2, wc = w & 3;                   // 2(M) x 4(N)
  int bid = blockIdx.x;
  int per = gridDim.x >> 3;
  int g = (bid & 7) * per + (bid >> 3);
  int mi = g >> 2, ni = g & 3;                   // 512 m-tiles x 4 n-tiles
  int mBase = mi * 128, nB = ni * 192, nBase = ni * 256;
  f32x4 acc[4][4] = {};

  auto stageA = [&](int t) {                     // 2 loads/thread -> As[t&1]
    int buf = t & 1;
    const us* aSrc = (t < 4) ? h : s;
    int kOff = (t & 3) * 64;
#pragma unroll
    for (int c = 0; c < 2; ++c) {
      int row = c * 64 + (tid >> 3);
      int kb = ((tid & 7) * 16) ^ ((row & 7) << 4);
      gload_lds16((const char*)(aSrc + (size_t)(mBase + row) * 256 + kOff) + kb,
                  (char*)As[buf] + row * 128 + (tid & 7) * 16);
    }
  };
  auto stageBw = [&](int t) {                    // 3 loads/thread -> Bs[t&1]
    int buf = t & 1;
    const us* bSrc = (t < 4) ? Wgh : Wgs;
    int kOff = (t & 3) * 64;
#pragma unroll
    for (int c = 0; c < 3; ++c) {
      int row = c * 64 + (tid >> 3);
      int kb = ((tid & 7) * 16) ^ ((row & 7) << 4);
      gload_lds16((const char*)(bSrc + (size_t)(nB + row) * 256 + kOff) + kb,
                  (char*)Bs[buf] + row * 128 + (tid & 7) * 16);
    }
  };

  stageA(0); stageBw(0);
#pragma unroll
  for (int t = 0; t < 8; ++t) {
    if (t + 1 < 8) {
      stageA(t + 1); stageBw(t + 1);
      asm volatile("s_waitcnt vmcnt(5)" ::: "memory");  // tile t done; t+1's 5 in flight
    } else {
      asm volatile("s_waitcnt vmcnt(0)" ::: "memory");
    }
    raw_barrier();
    const us* A = As[t & 1];
    const us* B = Bs[t & 1];
    if (t < 4) {
      mma4g_ks<0, 0>(A, B, wr, wc, l, acc);      // slot2 -> xn
      mma4g_ks<0, 1>(A, B, wr, wc, l, acc);
    } else {
      mma4g_ks<1, 0>(A, B, wr, wc, l, acc);      // slot2 -> hn
      mma4g_ks<1, 1>(A, B, wr, wc, l, acc);
    }
    raw_barrier();
  }

  // shuffle-free GRU epilogue: acc j == gate {r, z, xn, hn}
  int rBase0 = mBase + wr * 64;
  int cB = nBase + wc * 64;
  int outCol = ((nBase >> 6) + wc) * 16 + (l & 15);
  float b0 = bg[cB + 0  + (l & 15)];
  float b1 = bg[cB + 16 + (l & 15)];
  float b2 = bg[cB + 32 + (l & 15)];
  float b3 = bg[cB + 48 + (l & 15)];
#pragma unroll
  for (int i = 0; i < 4; ++i) {
    int row0 = rBase0 + i * 16 + ((l >> 4) << 2);
#pragma unroll
    for (int e = 0; e < 4; ++e) {
      float r = sigf(acc[i][0][e] + b0);
      float z = sigf(acc[i][1][e] + b1);
      float n = tanhfast(acc[i][2][e] + b2 + r * (acc[i][3][e] + b3));
      size_t off = (size_t)(row0 + e) * 256 + outCol;
      float sv = finalIt ? sF[off] : bf2f(svBf[off]);
      float o = (1.f - z) * n + z * sv;
      if (finalIt) outF[off] = o;
      else         outBf[off] = f2bf(o);
    }
  }
}

extern "C" void kernel_launch(void* const* d_in, const int* in_sizes, int n_in,
                              void* d_out, int out_size, void* d_ws, size_t ws_size,
                              hipStream_t stream) {
  const float* x    = (const float*)d_in[0];
  const int*   par  = (const int*)d_in[1];
  const int*   chd  = (const int*)d_in[2];
  const int*   cnt  = (const int*)d_in[3];
  const float* Wres = (const float*)d_in[4];
  const float* bres = (const float*)d_in[5];
  const float* Wpar = (const float*)d_in[6];
  const float* bpar = (const float*)d_in[7];
  const float* Wnbr = (const float*)d_in[8];
  const float* bnbr = (const float*)d_in[9];
  const float* Wih  = (const float*)d_in[10];
  const float* Whh  = (const float*)d_in[11];
  const float* bih  = (const float*)d_in[12];
  const float* bhh  = (const float*)d_in[13];

  char* ws = (char*)d_ws;
  size_t off = 0;
  auto alloc = [&](size_t sz) { char* p = ws + off; off += (sz + 255) & ~(size_t)255; return p; };
  us*    Wgh  = (us*)alloc((size_t)768 * 256 * 2);
  us*    Wgs  = (us*)alloc((size_t)768 * 256 * 2);
  us*    Wcat = (us*)alloc((size_t)256 * 512 * 2);
  us*    Wr   = (us*)alloc((size_t)256 * 256 * 2);
  float* bcat = (float*)alloc(256 * 4);
  float* bg   = (float*)alloc(1024 * 4);
  us*    sbf  = (us*)alloc((size_t)MM * 256 * 2);
  us*    h0   = (us*)alloc((size_t)MM * 256 * 2);
  us*    h1   = (us*)alloc((size_t)MM * 256 * 2);
  float* sF   = (float*)d_out;  // f32 s scratch in d_out (final iter only;
                                // each slot overwritten after its own sv read)

  k_prep<<<256, 256, 0, stream>>>(Wres, Wpar, bpar, Wnbr, bnbr, Wih, Whh, bih, bhh,
                                  Wr, Wcat, bcat, Wgh, Wgs, bg);

  // h0 = x(f32) @ W_resize^T + b_resize   (direct f32 read)
  k_gemm0<<<256, 512, 0, stream>>>(x, Wr, bres, h0);

  us* hc = h0;
  for (int it = 0; it < 3; ++it) {
    us* hn = (hc == h0) ? h1 : h0;
    // s = [h[par] | avg(h[children])] @ Wcat^T + bcat
    k_sgemm<<<1024, 512, 0, stream>>>(hc, par, chd, cnt, Wcat, bcat,
                                      sbf, sF, (it == 2) ? 1 : 0);
    // gates = [h|s] @ packed-Wg, fused GRU -> h_next (bf16) or d_out (f32)
    k_gates<<<2048, 512, 0, stream>>>(
        hc, sbf, Wgh, Wgs, bg, hn, (float*)d_out, sbf, sF, (it == 2) ? 1 : 0);
    hc = hn;
  }
}

// Round 24
// 385.377 us; speedup vs baseline: 1.0682x; 1.0682x over previous
//
#include <hip/hip_runtime.h>

typedef unsigned short us;
typedef us us4 __attribute__((ext_vector_type(4)));
typedef us us8 __attribute__((ext_vector_type(8)));
typedef short bf16x8 __attribute__((ext_vector_type(8)));
typedef float f32x4 __attribute__((ext_vector_type(4)));

#define DEVI static __device__ __forceinline__

// constants for this problem instance
#define BB 16
#define NN 4096
#define PP 256
#define CC 8
#define MM (BB * NN)   // 65536

DEVI float bf2f(us u) { unsigned x = ((unsigned)u) << 16; return __builtin_bit_cast(float, x); }
DEVI us f2bf(float f) {
  unsigned x = __builtin_bit_cast(unsigned, f);
  x += 0x7fffu + ((x >> 16) & 1u);   // round to nearest even
  return (us)(x >> 16);
}

DEVI void gload_lds16(const void* g, void* l) {
  __builtin_amdgcn_global_load_lds(
      (const __attribute__((address_space(1))) void*)g,
      (__attribute__((address_space(3))) void*)l, 16, 0, 0);
}

DEVI float sigf(float x) { return 1.f / (1.f + __expf(-x)); }
DEVI float tanhfast(float a) {
  float aa = fabsf(a);
  float t = 1.f - 2.f / (1.f + __expf(2.f * aa));
  return copysignf(t, a);
}

DEVI void raw_barrier() {
  __builtin_amdgcn_sched_barrier(0);
  __builtin_amdgcn_s_barrier();      // RAW barrier: no implicit vmcnt(0) drain
  __builtin_amdgcn_sched_barrier(0);
}

// ---------------- weight prep ---------------------------------------------------
// Wcat[256][512] = [W_parent | W_nbr]; bcat = bpar + bnbr.
// Packed gates weights (192-row B-tiles, no dead rows):
//   Wgh[768][256] (h-half, from Wih) / Wgs[768][256] (s-half, from Whh):
//   row R -> J16 = R/48, slot = (R/16)%3; j_out = J16*16 + (R&15);
//   slot 0 = r, slot 1 = z, slot 2 = n (xn / hn).
__global__ void k_prep(const float* __restrict__ Wres,
                       const float* __restrict__ Wpar, const float* __restrict__ bpar,
                       const float* __restrict__ Wnbr, const float* __restrict__ bnbr,
                       const float* __restrict__ Wih, const float* __restrict__ Whh,
                       const float* __restrict__ bih, const float* __restrict__ bhh,
                       us* __restrict__ Wr, us* __restrict__ Wcat, float* __restrict__ bcat,
                       us* __restrict__ Wgh, us* __restrict__ Wgs, float* __restrict__ bg) {
  int tid = blockIdx.x * blockDim.x + threadIdx.x;
  int nth = gridDim.x * blockDim.x;
  for (int i = tid; i < 256 * 256; i += nth) Wr[i] = f2bf(Wres[i]);
  for (int i = tid; i < 256 * 512; i += nth) {
    int o = i >> 9, k = i & 511;
    float v = (k < 256) ? Wpar[o * 256 + k] : Wnbr[o * 256 + (k - 256)];
    Wcat[i] = f2bf(v);
  }
  for (int i = tid; i < 256; i += nth) bcat[i] = bpar[i] + bnbr[i];
  for (int i = tid; i < 768 * 256; i += nth) {
    int R = i >> 8, k = i & 255;
    int j = (R / 48) * 16 + (R & 15);
    int slot = (R >> 4) % 3;                     // 0=r 1=z 2=n
    Wgh[i] = f2bf(Wih[(size_t)(slot * 256 + j) * 256 + k]);
    Wgs[i] = f2bf(Whh[(size_t)(slot * 256 + j) * 256 + k]);
  }
  for (int i = tid; i < 1024; i += nth) {
    int g = (i >> 4) & 3, j = ((i >> 6) << 4) + (i & 15);
    float v;
    if (g == 0)      v = bih[j] + bhh[j];
    else if (g == 1) v = bih[256 + j] + bhh[256 + j];
    else if (g == 2) v = bih[512 + j];
    else             v = bhh[512 + j];
    bg[i] = v;
  }
}

// ---------------- MFMA K-step (256x256 tile), full 4-j --------------------------
DEVI void mma8(const us* As, const us* Bs, int wr, int wc, int l,
               f32x4 (&acc)[8][4]) {
#pragma unroll
  for (int ks = 0; ks < 2; ++ks) {
    bf16x8 af[8], bfr[4];
#pragma unroll
    for (int i = 0; i < 8; ++i) {
      int row = wr * 128 + i * 16 + (l & 15);
      int kb = ((ks * 32 + (l >> 4) * 8) * 2) ^ ((row & 7) << 4);  // swizzled read
      af[i] = *(const bf16x8*)((const char*)As + row * 128 + kb);
    }
#pragma unroll
    for (int j = 0; j < 4; ++j) {
      int row = wc * 64 + j * 16 + (l & 15);
      int kb = ((ks * 32 + (l >> 4) * 8) * 2) ^ ((row & 7) << 4);
      bfr[j] = *(const bf16x8*)((const char*)Bs + row * 128 + kb);
    }
#pragma unroll
    for (int i = 0; i < 8; ++i)
#pragma unroll
      for (int j = 0; j < 4; ++j)
        acc[i][j] = __builtin_amdgcn_mfma_f32_16x16x32_bf16(af[i], bfr[j], acc[i][j], 0, 0, 0);
  }
}

// ---------------- MFMA phase (gates): one ks, per-wave M=64, packed B ----------
// slot 2 -> acc[.][2] (xn) on h-half (HN=0), acc[.][3] (hn) on s-half (HN=1).
template <int HN, int KS>
DEVI void mma4g_ks(const us* As, const us* Bs, int wr, int wc, int l,
                   f32x4 (&acc)[4][4]) {
  bf16x8 af[4], bfr[3];
#pragma unroll
  for (int i = 0; i < 4; ++i) {
    int row = wr * 64 + i * 16 + (l & 15);
    int kb = ((KS * 32 + (l >> 4) * 8) * 2) ^ ((row & 7) << 4);
    af[i] = *(const bf16x8*)((const char*)As + row * 128 + kb);
  }
#pragma unroll
  for (int j = 0; j < 3; ++j) {
    int row = wc * 48 + j * 16 + (l & 15);
    int kb = ((KS * 32 + (l >> 4) * 8) * 2) ^ ((row & 7) << 4);
    bfr[j] = *(const bf16x8*)((const char*)Bs + row * 128 + kb);
  }
  __builtin_amdgcn_s_setprio(1);
#pragma unroll
  for (int i = 0; i < 4; ++i)
#pragma unroll
    for (int j = 0; j < 3; ++j) {
      int aj = (j < 2) ? j : (HN ? 3 : 2);
      acc[i][aj] = __builtin_amdgcn_mfma_f32_16x16x32_bf16(af[i], bfr[j], acc[i][aj], 0, 0, 0);
    }
  __builtin_amdgcn_s_setprio(0);
}

// ---------------- resize GEMM: h0 = x(f32) @ Wr^T + bres -----------------------
__global__ __launch_bounds__(512, 2)
void k_gemm0(const float* __restrict__ x, const us* __restrict__ Bw,
             const float* __restrict__ bias, us* __restrict__ outBf) {
  __shared__ __align__(16) us As[256 * 64];
  __shared__ __align__(16) us Bs[256 * 64];
  int tid = threadIdx.x;
  int w = tid >> 6, l = tid & 63;
  int wr = w >> 2, wc = w & 3;
  int bid = blockIdx.x;
  int per = gridDim.x >> 3;
  int mi = (bid & 7) * per + (bid >> 3);
  int mBase = mi * 256;
  f32x4 acc[8][4] = {};

#pragma unroll
  for (int t = 0; t < 4; ++t) {
    int kt = t * 64;
#pragma unroll
    for (int c = 0; c < 4; ++c) {
      int row = c * 64 + (tid >> 3);
      int kbb = ((tid & 7) * 16) ^ ((row & 7) << 4);   // bf16-byte offset (swizzled src)
      const float* src = x + (size_t)(mBase + row) * 256 + kt + (kbb >> 1);
      float4 a = *(const float4*)src;
      float4 b = *(const float4*)(src + 4);
      us8 v;
      v[0] = f2bf(a.x); v[1] = f2bf(a.y); v[2] = f2bf(a.z); v[3] = f2bf(a.w);
      v[4] = f2bf(b.x); v[5] = f2bf(b.y); v[6] = f2bf(b.z); v[7] = f2bf(b.w);
      *(us8*)((char*)As + row * 128 + (tid & 7) * 16) = v;  // linear dest
      int kb = ((tid & 7) * 16) ^ ((row & 7) << 4);
      gload_lds16((const char*)(Bw + (size_t)row * 256 + kt) + kb,
                  (char*)Bs + row * 128 + (tid & 7) * 16);
    }
    asm volatile("s_waitcnt vmcnt(0)" ::: "memory");
    __syncthreads();                  // drains lgkm (ds_writes) + barrier
    mma8(As, Bs, wr, wc, l, acc);
    __syncthreads();
  }

  int rBase0 = mBase + wr * 128;
  int cBase0 = wc * 64;
#pragma unroll
  for (int i = 0; i < 8; ++i)
#pragma unroll
    for (int j = 0; j < 4; ++j) {
      int col = cBase0 + j * 16 + (l & 15);
      int row0 = rBase0 + i * 16 + ((l >> 4) << 2);
      float bb = bias[col];
#pragma unroll
      for (int e = 0; e < 4; ++e)
        outBf[(size_t)(row0 + e) * 256 + col] = f2bf(acc[i][j][e] + bb);
    }
}

// ---------------- s GEMM: s = [h[par] | avg(h[children])] @ Wcat^T + bcat ------
// R22/R18 form (256-tile, gather computed ONCE per m-panel). R23's n-split
// duplicated the VALU-heavy children-gather 2x and regressed +25 µs — reverted.
__global__ __launch_bounds__(512, 2)
void k_sgemm(const us* __restrict__ h, const int* __restrict__ par,
             const int* __restrict__ chd, const int* __restrict__ cnt,
             const us* __restrict__ Wcat, const float* __restrict__ bcat,
             us* __restrict__ outBf, float* __restrict__ outF, int writeF32) {
  __shared__ __align__(16) us As[2][256 * 64];
  __shared__ __align__(16) us Bs[2][256 * 64];
  int tid = threadIdx.x;
  int w = tid >> 6, l = tid & 63;
  int wr = w >> 2, wc = w & 3;
  int bid = blockIdx.x;
  int per = gridDim.x >> 3;
  int mi = (bid & 7) * per + (bid >> 3);
  int mBase = mi * 256;
  int bb = (mBase >> 12) << 12;       // batch base row
  f32x4 acc[8][4] = {};

  int prow[4];
#pragma unroll
  for (int c = 0; c < 4; ++c)
    prow[c] = bb + par[mBase + c * 64 + (tid >> 3)];

  auto stageB = [&](int t) {
    int kt = t * 64, buf = t & 1;
#pragma unroll
    for (int c = 0; c < 4; ++c) {
      int row = c * 64 + (tid >> 3);
      int kb = ((tid & 7) * 16) ^ ((row & 7) << 4);
      gload_lds16((const char*)(Wcat + (size_t)row * 512 + kt) + kb,
                  (char*)Bs[buf] + row * 128 + (tid & 7) * 16);
    }
  };
  auto stageG = [&](int t) {          // tiles 0..3: h[parent] via gload (GA)
    int kt = t * 64, buf = t & 1;
#pragma unroll
    for (int c = 0; c < 4; ++c) {
      int row = c * 64 + (tid >> 3);
      int kb = ((tid & 7) * 16) ^ ((row & 7) << 4);
      gload_lds16((const char*)(h + (size_t)prow[c] * 256 + kt) + kb,
                  (char*)As[buf] + row * 128 + (tid & 7) * 16);
    }
    stageB(t);
  };
  auto stageN = [&](int t) {          // tiles 4..7: inline children-average
    int kt = t * 64, buf = t & 1;
    int kOffBase = kt - 256;
#pragma unroll
    for (int c = 0; c < 4; ++c) {
      int row = c * 64 + (tid >> 3);
      int m = mBase + row;
      int kbb = ((tid & 7) * 16) ^ ((row & 7) << 4);
      const us* hb = h + (size_t)bb * 256 + kOffBase + (kbb >> 1);
      int4 c0 = *(const int4*)(chd + (size_t)m * CC);
      int4 c1 = *(const int4*)(chd + (size_t)m * CC + 4);
      int ci[8] = {c0.x, c0.y, c0.z, c0.w, c1.x, c1.y, c1.z, c1.w};
      int cn = cnt[m];
      float aa[8] = {0.f, 0.f, 0.f, 0.f, 0.f, 0.f, 0.f, 0.f};
#pragma unroll
      for (int r2 = 0; r2 < 2; ++r2) {           // two rounds of 4 children
        us8 cv[4];
#pragma unroll
        for (int i2 = 0; i2 < 4; ++i2)
          cv[i2] = *(const us8*)(hb + (size_t)ci[r2 * 4 + i2] * 256);
#pragma unroll
        for (int i2 = 0; i2 < 4; ++i2) {
          float wgt = (r2 * 4 + i2 < cn) ? 1.f : 0.f;
#pragma unroll
          for (int e = 0; e < 8; ++e) aa[e] += wgt * bf2f(cv[i2][e]);
        }
      }
      float inv = 1.f / (float)cn;
      us8 nb;
#pragma unroll
      for (int e = 0; e < 8; ++e) nb[e] = f2bf(aa[e] * inv);
      *(us8*)((char*)As[buf] + row * 128 + (tid & 7) * 16) = nb;
    }
    asm volatile("s_waitcnt lgkmcnt(0)" ::: "memory");  // ds_writes done pre-barrier
    stageB(t);
  };

  stageG(0);
#pragma unroll
  for (int t = 0; t < 8; ++t) {
    if (t + 1 < 8) {
      if (t + 1 < 4) stageG(t + 1);
      else           stageN(t + 1);
    }
    if (t + 1 < 4)      asm volatile("s_waitcnt vmcnt(8)" ::: "memory");
    else if (t < 7)     asm volatile("s_waitcnt vmcnt(4)" ::: "memory");
    else                asm volatile("s_waitcnt vmcnt(0)" ::: "memory");
    raw_barrier();
    mma8(As[t & 1], Bs[t & 1], wr, wc, l, acc);
    raw_barrier();
  }

  int rBase0 = mBase + wr * 128;
  int cBase0 = wc * 64;
#pragma unroll
  for (int i = 0; i < 8; ++i)
#pragma unroll
    for (int j = 0; j < 4; ++j) {
      int col = cBase0 + j * 16 + (l & 15);
      int row0 = rBase0 + i * 16 + ((l >> 4) << 2);
      float bbia = bcat[col];
#pragma unroll
      for (int e = 0; e < 4; ++e) {
        float v = acc[i][j][e] + bbia;
        size_t off = (size_t)(row0 + e) * 256 + col;
        outBf[off] = f2bf(v);
        if (writeF32) outF[off] = v;
      }
    }
}

// ---------------- gates GEMM: [h|s] @ packed-Wg, 128-row tile, 8 waves ---------
// R22 form — best measured (80 µs, zero spill, 4 waves/SIMD). Unchanged.
__global__ __launch_bounds__(512, 2)
void k_gates(const us* __restrict__ h, const us* __restrict__ s,
             const us* __restrict__ Wgh, const us* __restrict__ Wgs,
             const float* __restrict__ bg,
             us* __restrict__ outBf, float* __restrict__ outF,
             const us* __restrict__ svBf, const float* __restrict__ sF,
             int finalIt) {
  __shared__ __align__(16) us As[2][128 * 64];   // 32 KB
  __shared__ __align__(16) us Bs[2][192 * 64];   // 48 KB  (total 80 KB)
  int tid = threadIdx.x;
  int w = tid >> 6, l = tid & 63;
  int wr = w >> 2, wc = w & 3;                   // 2(M) x 4(N)
  int bid = blockIdx.x;
  int per = gridDim.x >> 3;
  int g = (bid & 7) * per + (bid >> 3);
  int mi = g >> 2, ni = g & 3;                   // 512 m-tiles x 4 n-tiles
  int mBase = mi * 128, nB = ni * 192, nBase = ni * 256;
  f32x4 acc[4][4] = {};

  auto stageA = [&](int t) {                     // 2 loads/thread -> As[t&1]
    int buf = t & 1;
    const us* aSrc = (t < 4) ? h : s;
    int kOff = (t & 3) * 64;
#pragma unroll
    for (int c = 0; c < 2; ++c) {
      int row = c * 64 + (tid >> 3);
      int kb = ((tid & 7) * 16) ^ ((row & 7) << 4);
      gload_lds16((const char*)(aSrc + (size_t)(mBase + row) * 256 + kOff) + kb,
                  (char*)As[buf] + row * 128 + (tid & 7) * 16);
    }
  };
  auto stageBw = [&](int t) {                    // 3 loads/thread -> Bs[t&1]
    int buf = t & 1;
    const us* bSrc = (t < 4) ? Wgh : Wgs;
    int kOff = (t & 3) * 64;
#pragma unroll
    for (int c = 0; c < 3; ++c) {
      int row = c * 64 + (tid >> 3);
      int kb = ((tid & 7) * 16) ^ ((row & 7) << 4);
      gload_lds16((const char*)(bSrc + (size_t)(nB + row) * 256 + kOff) + kb,
                  (char*)Bs[buf] + row * 128 + (tid & 7) * 16);
    }
  };

  stageA(0); stageBw(0);
#pragma unroll
  for (int t = 0; t < 8; ++t) {
    if (t + 1 < 8) {
      stageA(t + 1); stageBw(t + 1);
      asm volatile("s_waitcnt vmcnt(5)" ::: "memory");  // tile t done; t+1's 5 in flight
    } else {
      asm volatile("s_waitcnt vmcnt(0)" ::: "memory");
    }
    raw_barrier();
    const us* A = As[t & 1];
    const us* B = Bs[t & 1];
    if (t < 4) {
      mma4g_ks<0, 0>(A, B, wr, wc, l, acc);      // slot2 -> xn
      mma4g_ks<0, 1>(A, B, wr, wc, l, acc);
    } else {
      mma4g_ks<1, 0>(A, B, wr, wc, l, acc);      // slot2 -> hn
      mma4g_ks<1, 1>(A, B, wr, wc, l, acc);
    }
    raw_barrier();
  }

  // shuffle-free GRU epilogue: acc j == gate {r, z, xn, hn}
  int rBase0 = mBase + wr * 64;
  int cB = nBase + wc * 64;
  int outCol = ((nBase >> 6) + wc) * 16 + (l & 15);
  float b0 = bg[cB + 0  + (l & 15)];
  float b1 = bg[cB + 16 + (l & 15)];
  float b2 = bg[cB + 32 + (l & 15)];
  float b3 = bg[cB + 48 + (l & 15)];
#pragma unroll
  for (int i = 0; i < 4; ++i) {
    int row0 = rBase0 + i * 16 + ((l >> 4) << 2);
#pragma unroll
    for (int e = 0; e < 4; ++e) {
      float r = sigf(acc[i][0][e] + b0);
      float z = sigf(acc[i][1][e] + b1);
      float n = tanhfast(acc[i][2][e] + b2 + r * (acc[i][3][e] + b3));
      size_t off = (size_t)(row0 + e) * 256 + outCol;
      float sv = finalIt ? sF[off] : bf2f(svBf[off]);
      float o = (1.f - z) * n + z * sv;
      if (finalIt) outF[off] = o;
      else         outBf[off] = f2bf(o);
    }
  }
}

extern "C" void kernel_launch(void* const* d_in, const int* in_sizes, int n_in,
                              void* d_out, int out_size, void* d_ws, size_t ws_size,
                              hipStream_t stream) {
  const float* x    = (const float*)d_in[0];
  const int*   par  = (const int*)d_in[1];
  const int*   chd  = (const int*)d_in[2];
  const int*   cnt  = (const int*)d_in[3];
  const float* Wres = (const float*)d_in[4];
  const float* bres = (const float*)d_in[5];
  const float* Wpar = (const float*)d_in[6];
  const float* bpar = (const float*)d_in[7];
  const float* Wnbr = (const float*)d_in[8];
  const float* bnbr = (const float*)d_in[9];
  const float* Wih  = (const float*)d_in[10];
  const float* Whh  = (const float*)d_in[11];
  const float* bih  = (const float*)d_in[12];
  const float* bhh  = (const float*)d_in[13];

  char* ws = (char*)d_ws;
  size_t off = 0;
  auto alloc = [&](size_t sz) { char* p = ws + off; off += (sz + 255) & ~(size_t)255; return p; };
  us*    Wgh  = (us*)alloc((size_t)768 * 256 * 2);
  us*    Wgs  = (us*)alloc((size_t)768 * 256 * 2);
  us*    Wcat = (us*)alloc((size_t)256 * 512 * 2);
  us*    Wr   = (us*)alloc((size_t)256 * 256 * 2);
  float* bcat = (float*)alloc(256 * 4);
  float* bg   = (float*)alloc(1024 * 4);
  us*    sbf  = (us*)alloc((size_t)MM * 256 * 2);
  us*    h0   = (us*)alloc((size_t)MM * 256 * 2);
  us*    h1   = (us*)alloc((size_t)MM * 256 * 2);
  float* sF   = (float*)d_out;  // f32 s scratch in d_out (final iter only;
                                // each slot overwritten after its own sv read)

  k_prep<<<256, 256, 0, stream>>>(Wres, Wpar, bpar, Wnbr, bnbr, Wih, Whh, bih, bhh,
                                  Wr, Wcat, bcat, Wgh, Wgs, bg);

  // h0 = x(f32) @ W_resize^T + b_resize   (direct f32 read)
  k_gemm0<<<256, 512, 0, stream>>>(x, Wr, bres, h0);

  us* hc = h0;
  for (int it = 0; it < 3; ++it) {
    us* hn = (hc == h0) ? h1 : h0;
    // s = [h[par] | avg(h[children])] @ Wcat^T + bcat
    k_sgemm<<<256, 512, 0, stream>>>(hc, par, chd, cnt, Wcat, bcat,
                                     sbf, sF, (it == 2) ? 1 : 0);
    // gates = [h|s] @ packed-Wg, fused GRU -> h_next (bf16) or d_out (f32)
    k_gates<<<2048, 512, 0, stream>>>(
        hc, sbf, Wgh, Wgs, bg, hn, (float*)d_out, sbf, sF, (it == 2) ? 1 : 0);
    hc = hn;
  }
}